// Round 6
// baseline (119.860 us; speedup 1.0000x reference)
//
#include <hip/hip_runtime.h>

// ProbabilityAdjustedLoss: B=8388608 rows of (2 logits f32, 1 label i32) -> scalar mean.
// R4 post-mortem: load hoisting + cheap math = neutral; kernel pinned at ~30us vs
// ~15-19us read floor, FETCH_SIZE only 50/96 MB -> half the stream served by L3 hits.
// R5 theory: the L3-hit read path is the throttle (fills prove HBM does 6.5 TB/s).
// Fix: nontemporal (nt) loads bypass L2/L3 and stream straight from HBM.
// Diagnostic: FETCH_SIZE must jump to ~96 MB if nt takes effect.
// (R5 bench was a GPUAcquisitionTimeout — identical kernel resubmitted.)

#define B_TOTAL   8388608
#define INV_B     (1.0f / 8388608.0f)   // power of two, exact
#define EPS_LOSS  1e-8f

#define NBLOCK    2048
#define NTHREAD   256
#define NTOT      (NBLOCK * NTHREAD)            // 524288 threads
#define NITER     (B_TOTAL / 2 / NTOT)          // 8, exact (no tail)

typedef float f4 __attribute__((ext_vector_type(4)));
typedef int   i2 __attribute__((ext_vector_type(2)));

__device__ __forceinline__ float row_loss(float l0, float l1, int label) {
    float d = l1 - l0;
    // p = softmax prob of labeled class; select sign via XOR (labels are 0/1):
    //   label==0: p0 = 1/(1+e^d)   label==1: p1 = 1/(1+e^-d)
    float x = __int_as_float(__float_as_int(d) ^ (label << 31));
    float e = __expf(x);
    float p = __builtin_amdgcn_rcpf(1.0f + e);   // ~1 ulp; threshold is 2.5e-2
    bool chg   = (label != 0);
    float c    = chg ? 0.05f        : 0.95f;
    float b    = chg ? (1.0f/0.95f) : 10.0f;
    float a    = chg ? 2.0f         : 1.0f;
    float wmin = chg ? 0.5f         : 0.1f;
    float t = fmaxf(0.0f, p - c);
    float w = fmaxf(wmin, fmaf(-b, t, a));
    return -w * __logf(p + EPS_LOSS);
}

__global__ __launch_bounds__(NTHREAD, 8) void pal_loss_kernel(
        const f4* __restrict__ lg,   // 2 rows per f4: (l0,l1,l0,l1)
        const i2* __restrict__ lb,   // 2 labels per i2
        float* __restrict__ partials)
{
    int tid = blockIdx.x * NTHREAD + threadIdx.x;

    // All 16 loads issued up front, nontemporal (bypass L1/L2/L3, pure stream).
    f4 L[NITER];
    i2 Y[NITER];
    #pragma unroll
    for (int k = 0; k < NITER; ++k) {
        L[k] = __builtin_nontemporal_load(lg + tid + k * NTOT);
        Y[k] = __builtin_nontemporal_load(lb + tid + k * NTOT);
    }
    __builtin_amdgcn_sched_barrier(0);

    float acc = 0.0f;
    #pragma unroll
    for (int k = 0; k < NITER; ++k) {
        acc += row_loss(L[k].x, L[k].y, Y[k].x);
        acc += row_loss(L[k].z, L[k].w, Y[k].y);
    }

    // wave-64 down-reduce
    #pragma unroll
    for (int off = 32; off > 0; off >>= 1)
        acc += __shfl_down(acc, off, 64);

    __shared__ float wsum[NTHREAD / 64];
    int lane = threadIdx.x & 63;
    int wid  = threadIdx.x >> 6;
    if (lane == 0) wsum[wid] = acc;
    __syncthreads();

    if (threadIdx.x == 0)
        partials[blockIdx.x] = wsum[0] + wsum[1] + wsum[2] + wsum[3];
}

__global__ __launch_bounds__(NTHREAD) void pal_finalize_kernel(
        const float* __restrict__ partials,  // 2048 floats
        float* __restrict__ out)
{
    float acc = 0.0f;
    #pragma unroll
    for (int k = 0; k < NBLOCK / NTHREAD; ++k)
        acc += partials[threadIdx.x + k * NTHREAD];

    #pragma unroll
    for (int off = 32; off > 0; off >>= 1)
        acc += __shfl_down(acc, off, 64);

    __shared__ float wsum[NTHREAD / 64];
    int lane = threadIdx.x & 63;
    int wid  = threadIdx.x >> 6;
    if (lane == 0) wsum[wid] = acc;
    __syncthreads();

    if (threadIdx.x == 0)
        out[0] = (wsum[0] + wsum[1] + wsum[2] + wsum[3]) * INV_B;  // overwrites poison
}

extern "C" void kernel_launch(void* const* d_in, const int* in_sizes, int n_in,
                              void* d_out, int out_size, void* d_ws, size_t ws_size,
                              hipStream_t stream) {
    const f4* lg  = (const f4*)d_in[0];   // logits f32 (B,2) -> B/2 f4
    const i2* lb  = (const i2*)d_in[1];   // labels i32 (B,) -> B/2 i2
    float*    out = (float*)d_out;
    float*    ws  = (float*)d_ws;         // 2048 floats of scratch

    pal_loss_kernel<<<NBLOCK, NTHREAD, 0, stream>>>(lg, lb, ws);
    pal_finalize_kernel<<<1, NTHREAD, 0, stream>>>(ws, out);
}